// Round 3
// baseline (1332.183 us; speedup 1.0000x reference)
//
#include <hip/hip_runtime.h>

#define NN 100000        // nodes
#define NE 1600000       // edges
#define NRL 3            // relations
#define NG 1024          // graphs
#define NSEG (NRL * NN)  // 300000 segments
#define SCAN_BLOCK 1024
#define SCAN_NB ((NSEG + SCAN_BLOCK - 1) / SCAN_BLOCK)  // 293

// ---------------- embed + lin0 + relu ----------------
__global__ void k_embed(const int* __restrict__ x_idx,
                        const float* __restrict__ semb, const float* __restrict__ cemb,
                        const float* __restrict__ w, const float* __restrict__ b,
                        float* __restrict__ xout) {
    __shared__ float s_w[16 * 64];
    __shared__ float s_se[64], s_ce[64], s_b[64];
    int t = threadIdx.x;
    for (int i = t; i < 16 * 64; i += 256) s_w[i] = w[i];
    if (t < 64) { s_se[t] = semb[t]; s_ce[t] = cemb[t]; s_b[t] = b[t]; }
    __syncthreads();
    int gid = blockIdx.x * 256 + t;           // grid exactly NN*64/256
    int v = gid >> 6, h = gid & 63;
    int si = x_idx[2 * v], ci = x_idx[2 * v + 1];
    float acc = s_b[h];
#pragma unroll
    for (int d = 0; d < 8; ++d) acc += s_se[si * 8 + d] * s_w[d * 64 + h];
#pragma unroll
    for (int d = 0; d < 8; ++d) acc += s_ce[ci * 8 + d] * s_w[(8 + d) * 64 + h];
    xout[gid] = fmaxf(acc, 0.f);
}

// ---------------- CSR build ----------------
__global__ void k_hist(const int* __restrict__ ei, const int* __restrict__ et,
                       int* __restrict__ cnt) {
    int e = blockIdx.x * 256 + threadIdx.x;
    if (e >= NE) return;
    int dst = ei[NE + e];
    atomicAdd(&cnt[dst * 3 + et[e]], 1);
}

__global__ void k_scan_reduce(const int* __restrict__ cnt, int* __restrict__ bsum) {
    __shared__ int lds[256];
    int blk = blockIdx.x, t = threadIdx.x;
    int base = blk * SCAN_BLOCK + t * 4;
    int s = 0;
#pragma unroll
    for (int j = 0; j < 4; ++j) { int idx = base + j; if (idx < NSEG) s += cnt[idx]; }
    lds[t] = s; __syncthreads();
    for (int ofs = 128; ofs > 0; ofs >>= 1) {
        if (t < ofs) lds[t] += lds[t + ofs];
        __syncthreads();
    }
    if (t == 0) bsum[blk] = lds[0];
}

__global__ void k_scan_top(const int* __restrict__ bsum, int* __restrict__ goff,
                           int* __restrict__ off_last) {
    __shared__ int lds[512];
    int t = threadIdx.x;
    int v = (t < SCAN_NB) ? bsum[t] : 0;
    lds[t] = v; __syncthreads();
    for (int ofs = 1; ofs < 512; ofs <<= 1) {
        int x = lds[t];
        int y = (t >= ofs) ? lds[t - ofs] : 0;
        __syncthreads();
        lds[t] = x + y;
        __syncthreads();
    }
    if (t < SCAN_NB) goff[t] = lds[t] - v;     // exclusive block offsets
    if (t == SCAN_NB - 1) *off_last = lds[t];  // total = NE
}

__global__ void k_scan_final(const int* __restrict__ cnt, const int* __restrict__ goff,
                             int* __restrict__ off, int* __restrict__ pos) {
    __shared__ int lds[256];
    int blk = blockIdx.x, t = threadIdx.x;
    int base = blk * SCAN_BLOCK + t * 4;
    int v[4]; int s = 0;
#pragma unroll
    for (int j = 0; j < 4; ++j) { int idx = base + j; v[j] = (idx < NSEG) ? cnt[idx] : 0; s += v[j]; }
    lds[t] = s; __syncthreads();
    for (int ofs = 1; ofs < 256; ofs <<= 1) {
        int x = lds[t];
        int y = (t >= ofs) ? lds[t - ofs] : 0;
        __syncthreads();
        lds[t] = x + y;
        __syncthreads();
    }
    int run = goff[blk] + (lds[t] - s);
#pragma unroll
    for (int j = 0; j < 4; ++j) {
        int idx = base + j;
        if (idx < NSEG) { off[idx] = run; pos[idx] = run; run += v[j]; }
    }
}

__global__ void k_scatter(const int* __restrict__ ei, const int* __restrict__ et,
                          int* __restrict__ pos, int* __restrict__ esrc) {
    int e = blockIdx.x * 256 + threadIdx.x;
    if (e >= NE) return;
    int src = ei[e];
    int dst = ei[NE + e];
    int p = atomicAdd(&pos[dst * 3 + et[e]], 1);
    esrc[p] = src;
}

// ---------------- per-(r,dst) mean aggregation: wave per node ----------------
// Writes K[v][0:64)=mean_r0, [64:128)=mean_r1, [128:192)=mean_r2, [192:256)=x[v]
__global__ void k_agg(const float* __restrict__ xin, const int* __restrict__ off,
                      const int* __restrict__ esrc, float* __restrict__ K) {
    int wid = (blockIdx.x * 256 + threadIdx.x) >> 6;
    int lane = threadIdx.x & 63;
    if (wid >= NN) return;
    int v = wid;
    float* Kv = K + (size_t)v * 256;
#pragma unroll
    for (int r = 0; r < 3; ++r) {
        int s0 = off[v * 3 + r], s1 = off[v * 3 + r + 1];
        float acc0 = 0.f, acc1 = 0.f;
        int e = s0;
        for (; e + 8 <= s1; e += 8) {
            int i0 = esrc[e], i1 = esrc[e + 1], i2 = esrc[e + 2], i3 = esrc[e + 3];
            int i4 = esrc[e + 4], i5 = esrc[e + 5], i6 = esrc[e + 6], i7 = esrc[e + 7];
            float x0 = xin[(size_t)i0 * 64 + lane];
            float x1 = xin[(size_t)i1 * 64 + lane];
            float x2 = xin[(size_t)i2 * 64 + lane];
            float x3 = xin[(size_t)i3 * 64 + lane];
            float x4 = xin[(size_t)i4 * 64 + lane];
            float x5 = xin[(size_t)i5 * 64 + lane];
            float x6 = xin[(size_t)i6 * 64 + lane];
            float x7 = xin[(size_t)i7 * 64 + lane];
            acc0 += (x0 + x1) + (x2 + x3);
            acc1 += (x4 + x5) + (x6 + x7);
        }
        for (; e < s1; ++e) acc0 += xin[(size_t)esrc[e] * 64 + lane];
        Kv[r * 64 + lane] = (acc0 + acc1) / fmaxf((float)(s1 - s0), 1.f);
    }
    Kv[192 + lane] = xin[(size_t)v * 64 + lane];
}

// ---------------- dense transform: xout = relu(K @ [Wr0;Wr1;Wr2;Wroot] + b) ----------------
// Block = 1024 threads (16 waves) sharing ONE 64KB W buffer -> 2 blocks/CU = 32 waves/CU.
// Wave handles 8 nodes, lane = h; each LDS W read feeds 8 FMAs.
__global__ __launch_bounds__(1024, 8) void k_transform(
        const float* __restrict__ K, const float* __restrict__ wrel,
        const float* __restrict__ wroot, const float* __restrict__ b,
        float* __restrict__ xout) {
    __shared__ float s_w[256 * 64];   // rows 0..191 = wrel (r,din), rows 192..255 = wroot
    __shared__ float s_b[64];
    int t = threadIdx.x;
    for (int i = t; i < 192 * 64; i += 1024) s_w[i] = wrel[i];
    for (int i = t; i < 64 * 64; i += 1024) s_w[192 * 64 + i] = wroot[i];
    if (t < 64) s_b[t] = b[t];
    __syncthreads();

    int wave = t >> 6, lane = t & 63;
    int v0 = blockIdx.x * 128 + wave * 8;   // 16 waves * 8 nodes = 128 nodes/block

    const float* Kp[8];
    float acc[8];
    float bb = s_b[lane];
#pragma unroll
    for (int n = 0; n < 8; ++n) {
        int v = v0 + n;
        if (v >= NN) v = NN - 1;           // clamp tail (store is guarded below)
        Kp[n] = K + (size_t)v * 256;
        acc[n] = bb;
    }

    for (int d4 = 0; d4 < 64; ++d4) {
        float w0 = s_w[(d4 * 4 + 0) * 64 + lane];
        float w1 = s_w[(d4 * 4 + 1) * 64 + lane];
        float w2 = s_w[(d4 * 4 + 2) * 64 + lane];
        float w3 = s_w[(d4 * 4 + 3) * 64 + lane];
#pragma unroll
        for (int n = 0; n < 8; ++n) {
            float4 p = *reinterpret_cast<const float4*>(Kp[n] + d4 * 4);
            acc[n] += p.x * w0 + p.y * w1 + p.z * w2 + p.w * w3;
        }
    }

#pragma unroll
    for (int n = 0; n < 8; ++n) {
        int v = v0 + n;
        if (v < NN) xout[(size_t)v * 64 + lane] = fmaxf(acc[n], 0.f);
    }
}

// ---------------- global mean pool: wave-segmented over sorted batch ----------------
#define POOL_CHUNK 32
__global__ void k_pool(const float* __restrict__ x, const int* __restrict__ batch,
                       float* __restrict__ psum, int* __restrict__ pcnt) {
    int gwid = (blockIdx.x * 256 + threadIdx.x) >> 6;
    int lane = threadIdx.x & 63;
    int v0 = gwid * POOL_CHUNK;
    if (v0 >= NN) return;
    int v1 = v0 + POOL_CHUNK; if (v1 > NN) v1 = NN;
    float acc = 0.f;
    int cnt = 0;
    int gcur = batch[v0];
    for (int v = v0; v < v1; ++v) {
        int g = batch[v];
        if (g != gcur) {
            atomicAdd(&psum[gcur * 64 + lane], acc);
            if (lane == 0) atomicAdd(&pcnt[gcur], cnt);
            acc = 0.f; cnt = 0; gcur = g;
        }
        acc += x[(size_t)v * 64 + lane];
        ++cnt;
    }
    atomicAdd(&psum[gcur * 64 + lane], acc);
    if (lane == 0) atomicAdd(&pcnt[gcur], cnt);
}

__global__ void k_cls(const float* __restrict__ psum, const int* __restrict__ pcnt,
                      const float* __restrict__ w, const float* __restrict__ b,
                      float* __restrict__ out) {
    int gid = blockIdx.x * 256 + threadIdx.x;
    if (gid >= NG * 10) return;
    int g = gid / 10, c = gid % 10;
    float inv = 1.f / fmaxf((float)pcnt[g], 1.f);
    float acc = 0.f;
#pragma unroll
    for (int d = 0; d < 64; ++d) acc += psum[g * 64 + d] * w[d * 10 + c];
    out[gid] = acc * inv + b[c];
}

extern "C" void kernel_launch(void* const* d_in, const int* in_sizes, int n_in,
                              void* d_out, int out_size, void* d_ws, size_t ws_size,
                              hipStream_t stream) {
    const int*   x_idx  = (const int*)d_in[0];
    const int*   ei     = (const int*)d_in[1];
    const int*   et     = (const int*)d_in[2];
    const int*   batch  = (const int*)d_in[3];
    const float* semb   = (const float*)d_in[4];
    const float* cemb   = (const float*)d_in[5];
    const float* lin0w  = (const float*)d_in[6];
    const float* lin0b  = (const float*)d_in[7];
    const float* r1wrel = (const float*)d_in[8];
    const float* r1wroot= (const float*)d_in[9];
    const float* r1b    = (const float*)d_in[10];
    const float* r2wrel = (const float*)d_in[11];
    const float* r2wroot= (const float*)d_in[12];
    const float* r2b    = (const float*)d_in[13];
    const float* clsw   = (const float*)d_in[14];
    const float* clsb   = (const float*)d_in[15];
    float* out = (float*)d_out;

    char* ws = (char*)d_ws;
    size_t o = 0;
    auto alloc = [&](size_t bytes) -> void* {
        void* p = ws + o;
        o += (bytes + 255) & ~(size_t)255;
        return p;
    };
    int*   off  = (int*)  alloc((size_t)(NSEG + 1) * 4);
    int*   pos  = (int*)  alloc((size_t)NSEG * 4);
    int*   cnt  = (int*)  alloc((size_t)NSEG * 4);
    int*   bsum = (int*)  alloc((size_t)SCAN_NB * 4);
    int*   goff = (int*)  alloc((size_t)SCAN_NB * 4);
    int*   esrc = (int*)  alloc((size_t)NE * 4);
    float* xA   = (float*)alloc((size_t)NN * 64 * 4);
    float* xB   = (float*)alloc((size_t)NN * 64 * 4);
    float* Kbuf = (float*)alloc((size_t)NN * 256 * 4);
    float* psum = (float*)alloc((size_t)NG * 64 * 4);
    int*   pcnt = (int*)  alloc((size_t)NG * 4);

    hipMemsetAsync(cnt, 0, (size_t)NSEG * 4, stream);
    hipMemsetAsync(psum, 0, (size_t)NG * 64 * 4, stream);
    hipMemsetAsync(pcnt, 0, (size_t)NG * 4, stream);

    // node features
    k_embed<<<NN * 64 / 256, 256, 0, stream>>>(x_idx, semb, cemb, lin0w, lin0b, xA);

    // CSR (built once, reused for both layers)
    k_hist<<<NE / 256, 256, 0, stream>>>(ei, et, cnt);
    k_scan_reduce<<<SCAN_NB, 256, 0, stream>>>(cnt, bsum);
    k_scan_top<<<1, 512, 0, stream>>>(bsum, goff, off + NSEG);
    k_scan_final<<<SCAN_NB, 256, 0, stream>>>(cnt, goff, off, pos);
    k_scatter<<<NE / 256, 256, 0, stream>>>(ei, et, pos, esrc);

    // layer 1
    k_agg<<<NN / 4, 256, 0, stream>>>(xA, off, esrc, Kbuf);
    k_transform<<<(NN + 127) / 128, 1024, 0, stream>>>(Kbuf, r1wrel, r1wroot, r1b, xB);
    // layer 2
    k_agg<<<NN / 4, 256, 0, stream>>>(xB, off, esrc, Kbuf);
    k_transform<<<(NN + 127) / 128, 1024, 0, stream>>>(Kbuf, r2wrel, r2wroot, r2b, xA);

    // pool + classify
    {
        int nwaves = (NN + POOL_CHUNK - 1) / POOL_CHUNK;        // 3125
        int nblk = (nwaves * 64 + 255) / 256;                   // 782
        k_pool<<<nblk, 256, 0, stream>>>(xA, batch, psum, pcnt);
    }
    k_cls<<<(NG * 10 + 255) / 256, 256, 0, stream>>>(psum, pcnt, clsw, clsb, out);
}

// Round 4
// 803.827 us; speedup vs baseline: 1.6573x; 1.6573x over previous
//
#include <hip/hip_runtime.h>

#define NN 100000        // nodes
#define NE 1600000       // edges
#define NRL 3            // relations
#define NG 1024          // graphs
#define NSEG (NRL * NN)  // 300000 segments
#define SCAN_BLOCK 1024
#define SCAN_NB ((NSEG + SCAN_BLOCK - 1) / SCAN_BLOCK)  // 293

__device__ __forceinline__ float rdlane(float v, int l) {
    return __uint_as_float(__builtin_amdgcn_readlane(__float_as_uint(v), l));
}

// ---------------- embed + lin0 + relu ----------------
__global__ void k_embed(const int* __restrict__ x_idx,
                        const float* __restrict__ semb, const float* __restrict__ cemb,
                        const float* __restrict__ w, const float* __restrict__ b,
                        float* __restrict__ xout) {
    __shared__ float s_w[16 * 64];
    __shared__ float s_se[64], s_ce[64], s_b[64];
    int t = threadIdx.x;
    for (int i = t; i < 16 * 64; i += 256) s_w[i] = w[i];
    if (t < 64) { s_se[t] = semb[t]; s_ce[t] = cemb[t]; s_b[t] = b[t]; }
    __syncthreads();
    int gid = blockIdx.x * 256 + t;           // grid exactly NN*64/256
    int v = gid >> 6, h = gid & 63;
    int si = x_idx[2 * v], ci = x_idx[2 * v + 1];
    float acc = s_b[h];
#pragma unroll
    for (int d = 0; d < 8; ++d) acc += s_se[si * 8 + d] * s_w[d * 64 + h];
#pragma unroll
    for (int d = 0; d < 8; ++d) acc += s_ce[ci * 8 + d] * s_w[(8 + d) * 64 + h];
    xout[gid] = fmaxf(acc, 0.f);
}

// ---------------- CSR build ----------------
__global__ void k_hist(const int* __restrict__ ei, const int* __restrict__ et,
                       int* __restrict__ cnt) {
    int e = blockIdx.x * 256 + threadIdx.x;
    if (e >= NE) return;
    int dst = ei[NE + e];
    atomicAdd(&cnt[dst * 3 + et[e]], 1);
}

__global__ void k_scan_reduce(const int* __restrict__ cnt, int* __restrict__ bsum) {
    __shared__ int lds[256];
    int blk = blockIdx.x, t = threadIdx.x;
    int base = blk * SCAN_BLOCK + t * 4;
    int s = 0;
#pragma unroll
    for (int j = 0; j < 4; ++j) { int idx = base + j; if (idx < NSEG) s += cnt[idx]; }
    lds[t] = s; __syncthreads();
    for (int ofs = 128; ofs > 0; ofs >>= 1) {
        if (t < ofs) lds[t] += lds[t + ofs];
        __syncthreads();
    }
    if (t == 0) bsum[blk] = lds[0];
}

__global__ void k_scan_top(const int* __restrict__ bsum, int* __restrict__ goff,
                           int* __restrict__ off_last) {
    __shared__ int lds[512];
    int t = threadIdx.x;
    int v = (t < SCAN_NB) ? bsum[t] : 0;
    lds[t] = v; __syncthreads();
    for (int ofs = 1; ofs < 512; ofs <<= 1) {
        int x = lds[t];
        int y = (t >= ofs) ? lds[t - ofs] : 0;
        __syncthreads();
        lds[t] = x + y;
        __syncthreads();
    }
    if (t < SCAN_NB) goff[t] = lds[t] - v;     // exclusive block offsets
    if (t == SCAN_NB - 1) *off_last = lds[t];  // total = NE
}

__global__ void k_scan_final(const int* __restrict__ cnt, const int* __restrict__ goff,
                             int* __restrict__ off, int* __restrict__ pos) {
    __shared__ int lds[256];
    int blk = blockIdx.x, t = threadIdx.x;
    int base = blk * SCAN_BLOCK + t * 4;
    int v[4]; int s = 0;
#pragma unroll
    for (int j = 0; j < 4; ++j) { int idx = base + j; v[j] = (idx < NSEG) ? cnt[idx] : 0; s += v[j]; }
    lds[t] = s; __syncthreads();
    for (int ofs = 1; ofs < 256; ofs <<= 1) {
        int x = lds[t];
        int y = (t >= ofs) ? lds[t - ofs] : 0;
        __syncthreads();
        lds[t] = x + y;
        __syncthreads();
    }
    int run = goff[blk] + (lds[t] - s);
#pragma unroll
    for (int j = 0; j < 4; ++j) {
        int idx = base + j;
        if (idx < NSEG) { off[idx] = run; pos[idx] = run; run += v[j]; }
    }
}

__global__ void k_scatter(const int* __restrict__ ei, const int* __restrict__ et,
                          int* __restrict__ pos, int* __restrict__ esrc) {
    int e = blockIdx.x * 256 + threadIdx.x;
    if (e >= NE) return;
    int src = ei[e];
    int dst = ei[NE + e];
    int p = atomicAdd(&pos[dst * 3 + et[e]], 1);
    esrc[p] = src;
}

// ---------------- per-(r,dst) mean aggregation: wave per node ----------------
// Writes K[v][0:64)=mean_r0, [64:128)=mean_r1, [128:192)=mean_r2, [192:256)=x[v]
__global__ void k_agg(const float* __restrict__ xin, const int* __restrict__ off,
                      const int* __restrict__ esrc, float* __restrict__ K) {
    int wid = (blockIdx.x * 256 + threadIdx.x) >> 6;
    int lane = threadIdx.x & 63;
    if (wid >= NN) return;
    int v = wid;
    float* Kv = K + (size_t)v * 256;
#pragma unroll
    for (int r = 0; r < 3; ++r) {
        int s0 = off[v * 3 + r], s1 = off[v * 3 + r + 1];
        float acc0 = 0.f, acc1 = 0.f;
        int e = s0;
        for (; e + 8 <= s1; e += 8) {
            int i0 = esrc[e], i1 = esrc[e + 1], i2 = esrc[e + 2], i3 = esrc[e + 3];
            int i4 = esrc[e + 4], i5 = esrc[e + 5], i6 = esrc[e + 6], i7 = esrc[e + 7];
            float x0 = xin[(size_t)i0 * 64 + lane];
            float x1 = xin[(size_t)i1 * 64 + lane];
            float x2 = xin[(size_t)i2 * 64 + lane];
            float x3 = xin[(size_t)i3 * 64 + lane];
            float x4 = xin[(size_t)i4 * 64 + lane];
            float x5 = xin[(size_t)i5 * 64 + lane];
            float x6 = xin[(size_t)i6 * 64 + lane];
            float x7 = xin[(size_t)i7 * 64 + lane];
            acc0 += (x0 + x1) + (x2 + x3);
            acc1 += (x4 + x5) + (x6 + x7);
        }
        for (; e < s1; ++e) acc0 += xin[(size_t)esrc[e] * 64 + lane];
        Kv[r * 64 + lane] = (acc0 + acc1) / fmaxf((float)(s1 - s0), 1.f);
    }
    Kv[192 + lane] = xin[(size_t)v * 64 + lane];
}

// ---------------- dense transform: xout = relu(K @ [Wr0;Wr1;Wr2;Wroot] + b) ----------------
// 512 threads (8 waves). Wave owns 8 consecutive nodes = 8KB contiguous K slab,
// loaded COALESCED into registers (load j = node j's row; lane l holds floats 4l..4l+3).
// Inner loop is memory-free: K scalars broadcast via v_readlane (uniform d4), W from LDS.
__global__ __launch_bounds__(512, 4) void k_transform(
        const float* __restrict__ K, const float* __restrict__ wrel,
        const float* __restrict__ wroot, const float* __restrict__ b,
        float* __restrict__ xout) {
    __shared__ float s_w[256 * 64];   // rows 0..191 = wrel, rows 192..255 = wroot
    __shared__ float s_b[64];
    int t = threadIdx.x;
    for (int i = t; i < 192 * 64; i += 512) s_w[i] = wrel[i];
    for (int i = t; i < 64 * 64; i += 512) s_w[192 * 64 + i] = wroot[i];
    if (t < 64) s_b[t] = b[t];
    __syncthreads();

    int wave = t >> 6, lane = t & 63;
    int v0 = blockIdx.x * 64 + wave * 8;   // 8 waves * 8 nodes = 64 nodes/block
    if (v0 >= NN) return;                   // NN % 8 == 0: active waves fully valid

    // coalesced register tile: kreg[j] = K[v0+j][lane*4 .. +4)
    const float* base = K + (size_t)v0 * 256;
    float4 kreg[8];
#pragma unroll
    for (int j = 0; j < 8; ++j)
        kreg[j] = *reinterpret_cast<const float4*>(base + j * 256 + lane * 4);

    float acc[8];
    float bb = s_b[lane];
#pragma unroll
    for (int n = 0; n < 8; ++n) acc[n] = bb;

    for (int d4 = 0; d4 < 64; ++d4) {       // d4 uniform -> readlane index in SGPR
        float w0 = s_w[(d4 * 4 + 0) * 64 + lane];
        float w1 = s_w[(d4 * 4 + 1) * 64 + lane];
        float w2 = s_w[(d4 * 4 + 2) * 64 + lane];
        float w3 = s_w[(d4 * 4 + 3) * 64 + lane];
#pragma unroll
        for (int n = 0; n < 8; ++n) {
            float kx = rdlane(kreg[n].x, d4);
            float ky = rdlane(kreg[n].y, d4);
            float kz = rdlane(kreg[n].z, d4);
            float kw = rdlane(kreg[n].w, d4);
            acc[n] += kx * w0;
            acc[n] += ky * w1;
            acc[n] += kz * w2;
            acc[n] += kw * w3;
        }
    }

#pragma unroll
    for (int n = 0; n < 8; ++n)
        xout[(size_t)(v0 + n) * 64 + lane] = fmaxf(acc[n], 0.f);
}

// ---------------- global mean pool: wave-segmented over sorted batch ----------------
#define POOL_CHUNK 32
__global__ void k_pool(const float* __restrict__ x, const int* __restrict__ batch,
                       float* __restrict__ psum, int* __restrict__ pcnt) {
    int gwid = (blockIdx.x * 256 + threadIdx.x) >> 6;
    int lane = threadIdx.x & 63;
    int v0 = gwid * POOL_CHUNK;
    if (v0 >= NN) return;
    int v1 = v0 + POOL_CHUNK; if (v1 > NN) v1 = NN;
    float acc = 0.f;
    int cnt = 0;
    int gcur = batch[v0];
    for (int v = v0; v < v1; ++v) {
        int g = batch[v];
        if (g != gcur) {
            atomicAdd(&psum[gcur * 64 + lane], acc);
            if (lane == 0) atomicAdd(&pcnt[gcur], cnt);
            acc = 0.f; cnt = 0; gcur = g;
        }
        acc += x[(size_t)v * 64 + lane];
        ++cnt;
    }
    atomicAdd(&psum[gcur * 64 + lane], acc);
    if (lane == 0) atomicAdd(&pcnt[gcur], cnt);
}

__global__ void k_cls(const float* __restrict__ psum, const int* __restrict__ pcnt,
                      const float* __restrict__ w, const float* __restrict__ b,
                      float* __restrict__ out) {
    int gid = blockIdx.x * 256 + threadIdx.x;
    if (gid >= NG * 10) return;
    int g = gid / 10, c = gid % 10;
    float inv = 1.f / fmaxf((float)pcnt[g], 1.f);
    float acc = 0.f;
#pragma unroll
    for (int d = 0; d < 64; ++d) acc += psum[g * 64 + d] * w[d * 10 + c];
    out[gid] = acc * inv + b[c];
}

extern "C" void kernel_launch(void* const* d_in, const int* in_sizes, int n_in,
                              void* d_out, int out_size, void* d_ws, size_t ws_size,
                              hipStream_t stream) {
    const int*   x_idx  = (const int*)d_in[0];
    const int*   ei     = (const int*)d_in[1];
    const int*   et     = (const int*)d_in[2];
    const int*   batch  = (const int*)d_in[3];
    const float* semb   = (const float*)d_in[4];
    const float* cemb   = (const float*)d_in[5];
    const float* lin0w  = (const float*)d_in[6];
    const float* lin0b  = (const float*)d_in[7];
    const float* r1wrel = (const float*)d_in[8];
    const float* r1wroot= (const float*)d_in[9];
    const float* r1b    = (const float*)d_in[10];
    const float* r2wrel = (const float*)d_in[11];
    const float* r2wroot= (const float*)d_in[12];
    const float* r2b    = (const float*)d_in[13];
    const float* clsw   = (const float*)d_in[14];
    const float* clsb   = (const float*)d_in[15];
    float* out = (float*)d_out;

    char* ws = (char*)d_ws;
    size_t o = 0;
    auto alloc = [&](size_t bytes) -> void* {
        void* p = ws + o;
        o += (bytes + 255) & ~(size_t)255;
        return p;
    };
    int*   off  = (int*)  alloc((size_t)(NSEG + 1) * 4);
    int*   pos  = (int*)  alloc((size_t)NSEG * 4);
    int*   cnt  = (int*)  alloc((size_t)NSEG * 4);
    int*   bsum = (int*)  alloc((size_t)SCAN_NB * 4);
    int*   goff = (int*)  alloc((size_t)SCAN_NB * 4);
    int*   esrc = (int*)  alloc((size_t)NE * 4);
    float* xA   = (float*)alloc((size_t)NN * 64 * 4);
    float* xB   = (float*)alloc((size_t)NN * 64 * 4);
    float* Kbuf = (float*)alloc((size_t)NN * 256 * 4);
    float* psum = (float*)alloc((size_t)NG * 64 * 4);
    int*   pcnt = (int*)  alloc((size_t)NG * 4);

    hipMemsetAsync(cnt, 0, (size_t)NSEG * 4, stream);
    hipMemsetAsync(psum, 0, (size_t)NG * 64 * 4, stream);
    hipMemsetAsync(pcnt, 0, (size_t)NG * 4, stream);

    // node features
    k_embed<<<NN * 64 / 256, 256, 0, stream>>>(x_idx, semb, cemb, lin0w, lin0b, xA);

    // CSR (built once, reused for both layers)
    k_hist<<<NE / 256, 256, 0, stream>>>(ei, et, cnt);
    k_scan_reduce<<<SCAN_NB, 256, 0, stream>>>(cnt, bsum);
    k_scan_top<<<1, 512, 0, stream>>>(bsum, goff, off + NSEG);
    k_scan_final<<<SCAN_NB, 256, 0, stream>>>(cnt, goff, off, pos);
    k_scatter<<<NE / 256, 256, 0, stream>>>(ei, et, pos, esrc);

    // layer 1
    k_agg<<<NN / 4, 256, 0, stream>>>(xA, off, esrc, Kbuf);
    k_transform<<<(NN + 63) / 64, 512, 0, stream>>>(Kbuf, r1wrel, r1wroot, r1b, xB);
    // layer 2
    k_agg<<<NN / 4, 256, 0, stream>>>(xB, off, esrc, Kbuf);
    k_transform<<<(NN + 63) / 64, 512, 0, stream>>>(Kbuf, r2wrel, r2wroot, r2b, xA);

    // pool + classify
    {
        int nwaves = (NN + POOL_CHUNK - 1) / POOL_CHUNK;        // 3125
        int nblk = (nwaves * 64 + 255) / 256;                   // 782
        k_pool<<<nblk, 256, 0, stream>>>(xA, batch, psum, pcnt);
    }
    k_cls<<<(NG * 10 + 255) / 256, 256, 0, stream>>>(psum, pcnt, clsw, clsb, out);
}

// Round 5
// 577.757 us; speedup vs baseline: 2.3058x; 1.3913x over previous
//
#include <hip/hip_runtime.h>

#define NN 100000        // nodes
#define NE 1600000       // edges
#define NRL 3            // relations
#define NG 1024          // graphs
#define NSEG (NRL * NN)  // 300000 segments
#define SCAN_BLOCK 1024
#define SCAN_NB ((NSEG + SCAN_BLOCK - 1) / SCAN_BLOCK)  // 293

// ---------------- embed + lin0 + relu ----------------
__global__ void k_embed(const int* __restrict__ x_idx,
                        const float* __restrict__ semb, const float* __restrict__ cemb,
                        const float* __restrict__ w, const float* __restrict__ b,
                        float* __restrict__ xout) {
    __shared__ float s_w[16 * 64];
    __shared__ float s_se[64], s_ce[64], s_b[64];
    int t = threadIdx.x;
    for (int i = t; i < 16 * 64; i += 256) s_w[i] = w[i];
    if (t < 64) { s_se[t] = semb[t]; s_ce[t] = cemb[t]; s_b[t] = b[t]; }
    __syncthreads();
    int gid = blockIdx.x * 256 + t;           // grid exactly NN*64/256
    int v = gid >> 6, h = gid & 63;
    int si = x_idx[2 * v], ci = x_idx[2 * v + 1];
    float acc = s_b[h];
#pragma unroll
    for (int d = 0; d < 8; ++d) acc += s_se[si * 8 + d] * s_w[d * 64 + h];
#pragma unroll
    for (int d = 0; d < 8; ++d) acc += s_ce[ci * 8 + d] * s_w[(8 + d) * 64 + h];
    xout[gid] = fmaxf(acc, 0.f);
}

// ---------------- CSR build ----------------
__global__ void k_hist(const int* __restrict__ ei, const int* __restrict__ et,
                       int* __restrict__ cnt) {
    int e = blockIdx.x * 256 + threadIdx.x;
    if (e >= NE) return;
    int dst = ei[NE + e];
    atomicAdd(&cnt[dst * 3 + et[e]], 1);
}

__global__ void k_scan_reduce(const int* __restrict__ cnt, int* __restrict__ bsum) {
    __shared__ int lds[256];
    int blk = blockIdx.x, t = threadIdx.x;
    int base = blk * SCAN_BLOCK + t * 4;
    int s = 0;
#pragma unroll
    for (int j = 0; j < 4; ++j) { int idx = base + j; if (idx < NSEG) s += cnt[idx]; }
    lds[t] = s; __syncthreads();
    for (int ofs = 128; ofs > 0; ofs >>= 1) {
        if (t < ofs) lds[t] += lds[t + ofs];
        __syncthreads();
    }
    if (t == 0) bsum[blk] = lds[0];
}

__global__ void k_scan_top(const int* __restrict__ bsum, int* __restrict__ goff,
                           int* __restrict__ off_last) {
    __shared__ int lds[512];
    int t = threadIdx.x;
    int v = (t < SCAN_NB) ? bsum[t] : 0;
    lds[t] = v; __syncthreads();
    for (int ofs = 1; ofs < 512; ofs <<= 1) {
        int x = lds[t];
        int y = (t >= ofs) ? lds[t - ofs] : 0;
        __syncthreads();
        lds[t] = x + y;
        __syncthreads();
    }
    if (t < SCAN_NB) goff[t] = lds[t] - v;     // exclusive block offsets
    if (t == SCAN_NB - 1) *off_last = lds[t];  // total = NE
}

__global__ void k_scan_final(const int* __restrict__ cnt, const int* __restrict__ goff,
                             int* __restrict__ off, int* __restrict__ pos) {
    __shared__ int lds[256];
    int blk = blockIdx.x, t = threadIdx.x;
    int base = blk * SCAN_BLOCK + t * 4;
    int v[4]; int s = 0;
#pragma unroll
    for (int j = 0; j < 4; ++j) { int idx = base + j; v[j] = (idx < NSEG) ? cnt[idx] : 0; s += v[j]; }
    lds[t] = s; __syncthreads();
    for (int ofs = 1; ofs < 256; ofs <<= 1) {
        int x = lds[t];
        int y = (t >= ofs) ? lds[t - ofs] : 0;
        __syncthreads();
        lds[t] = x + y;
        __syncthreads();
    }
    int run = goff[blk] + (lds[t] - s);
#pragma unroll
    for (int j = 0; j < 4; ++j) {
        int idx = base + j;
        if (idx < NSEG) { off[idx] = run; pos[idx] = run; run += v[j]; }
    }
}

__global__ void k_scatter(const int* __restrict__ ei, const int* __restrict__ et,
                          int* __restrict__ pos, int* __restrict__ esrc) {
    int e = blockIdx.x * 256 + threadIdx.x;
    if (e >= NE) return;
    int src = ei[e];
    int dst = ei[NE + e];
    int p = atomicAdd(&pos[dst * 3 + et[e]], 1);
    esrc[p] = src;
}

// ---------------- per-(r,dst) mean aggregation: wave per node ----------------
// Single fused loop over the node's contiguous edge range [off[3v], off[3v+3]),
// relation selected by boundary compare (uniform). Offsets/indices via scalar path.
// Writes K[v][0:64)=mean_r0, [64:128)=mean_r1, [128:192)=mean_r2, [192:256)=x[v]
__global__ void k_agg(const float* __restrict__ xin, const int* __restrict__ off,
                      const int* __restrict__ esrc, float* __restrict__ K) {
    int wid = (blockIdx.x * 256 + threadIdx.x) >> 6;
    int lane = threadIdx.x & 63;
    if (wid >= NN) return;
    int v = wid;
    int b0 = __builtin_amdgcn_readfirstlane(off[v * 3 + 0]);
    int b1 = __builtin_amdgcn_readfirstlane(off[v * 3 + 1]);
    int b2 = __builtin_amdgcn_readfirstlane(off[v * 3 + 2]);
    int b3 = __builtin_amdgcn_readfirstlane(off[v * 3 + 3]);

    float a0 = 0.f, a1 = 0.f, a2 = 0.f;
    int e = b0;
    for (; e + 8 <= b3; e += 8) {
#pragma unroll
        for (int k = 0; k < 8; ++k) {
            int ee = e + k;
            int idx = esrc[ee];                       // uniform addr -> s_load
            float x = xin[(size_t)idx * 64 + lane];   // coalesced 256B gather
            a0 += (ee < b1) ? x : 0.f;
            a1 += (ee >= b1 && ee < b2) ? x : 0.f;
            a2 += (ee >= b2) ? x : 0.f;
        }
    }
    for (; e < b3; ++e) {
        int idx = esrc[e];
        float x = xin[(size_t)idx * 64 + lane];
        a0 += (e < b1) ? x : 0.f;
        a1 += (e >= b1 && e < b2) ? x : 0.f;
        a2 += (e >= b2) ? x : 0.f;
    }

    float* Kv = K + (size_t)v * 256;
    Kv[lane]        = a0 / fmaxf((float)(b1 - b0), 1.f);
    Kv[64 + lane]   = a1 / fmaxf((float)(b2 - b1), 1.f);
    Kv[128 + lane]  = a2 / fmaxf((float)(b3 - b2), 1.f);
    Kv[192 + lane]  = xin[(size_t)v * 64 + lane];
}

// ---------------- dense transform: xout = relu(K @ [Wr0;Wr1;Wr2;Wroot] + b) ----------------
// 512 threads (8 waves). Wave owns 8 consecutive nodes = 8KB K slab.
// K pointer readfirstlane'd -> uniform -> s_load_dwordx4 (SMEM pipe); FMA takes
// the K scalar as its SGPR operand. Inner loop: 4 LDS reads + 32 pure FMAs.
__global__ __launch_bounds__(512, 4) void k_transform(
        const float* __restrict__ K, const float* __restrict__ wrel,
        const float* __restrict__ wroot, const float* __restrict__ b,
        float* __restrict__ xout) {
    __shared__ float s_w[256 * 64];   // rows 0..191 = wrel, rows 192..255 = wroot
    __shared__ float s_b[64];
    int t = threadIdx.x;
    for (int i = t; i < 192 * 64; i += 512) s_w[i] = wrel[i];
    for (int i = t; i < 64 * 64; i += 512) s_w[192 * 64 + i] = wroot[i];
    if (t < 64) s_b[t] = b[t];
    __syncthreads();

    int wave = t >> 6, lane = t & 63;
    int v0 = blockIdx.x * 64 + wave * 8;   // 8 waves * 8 nodes = 64 nodes/block
    if (v0 >= NN) return;                   // NN % 8 == 0: active waves fully valid

    int v0u = __builtin_amdgcn_readfirstlane(v0);
    const float* Kb = K + (size_t)v0u * 256;   // uniform base -> scalar loads

    float acc[8];
    float bb = s_b[lane];
#pragma unroll
    for (int n = 0; n < 8; ++n) acc[n] = bb;

#pragma unroll 2
    for (int d4 = 0; d4 < 64; ++d4) {
        float w0 = s_w[(d4 * 4 + 0) * 64 + lane];
        float w1 = s_w[(d4 * 4 + 1) * 64 + lane];
        float w2 = s_w[(d4 * 4 + 2) * 64 + lane];
        float w3 = s_w[(d4 * 4 + 3) * 64 + lane];
#pragma unroll
        for (int n = 0; n < 8; ++n) {
            float k0 = Kb[n * 256 + d4 * 4 + 0];   // s_load_dwordx4
            float k1 = Kb[n * 256 + d4 * 4 + 1];
            float k2 = Kb[n * 256 + d4 * 4 + 2];
            float k3 = Kb[n * 256 + d4 * 4 + 3];
            acc[n] += k0 * w0;
            acc[n] += k1 * w1;
            acc[n] += k2 * w2;
            acc[n] += k3 * w3;
        }
    }

#pragma unroll
    for (int n = 0; n < 8; ++n)
        xout[(size_t)(v0 + n) * 64 + lane] = fmaxf(acc[n], 0.f);
}

// ---------------- global mean pool: wave-segmented over sorted batch ----------------
#define POOL_CHUNK 32
__global__ void k_pool(const float* __restrict__ x, const int* __restrict__ batch,
                       float* __restrict__ psum, int* __restrict__ pcnt) {
    int gwid = (blockIdx.x * 256 + threadIdx.x) >> 6;
    int lane = threadIdx.x & 63;
    int v0 = gwid * POOL_CHUNK;
    if (v0 >= NN) return;
    int v1 = v0 + POOL_CHUNK; if (v1 > NN) v1 = NN;
    float acc = 0.f;
    int cnt = 0;
    int gcur = batch[v0];
    for (int v = v0; v < v1; ++v) {
        int g = batch[v];
        if (g != gcur) {
            atomicAdd(&psum[gcur * 64 + lane], acc);
            if (lane == 0) atomicAdd(&pcnt[gcur], cnt);
            acc = 0.f; cnt = 0; gcur = g;
        }
        acc += x[(size_t)v * 64 + lane];
        ++cnt;
    }
    atomicAdd(&psum[gcur * 64 + lane], acc);
    if (lane == 0) atomicAdd(&pcnt[gcur], cnt);
}

__global__ void k_cls(const float* __restrict__ psum, const int* __restrict__ pcnt,
                      const float* __restrict__ w, const float* __restrict__ b,
                      float* __restrict__ out) {
    int gid = blockIdx.x * 256 + threadIdx.x;
    if (gid >= NG * 10) return;
    int g = gid / 10, c = gid % 10;
    float inv = 1.f / fmaxf((float)pcnt[g], 1.f);
    float acc = 0.f;
#pragma unroll
    for (int d = 0; d < 64; ++d) acc += psum[g * 64 + d] * w[d * 10 + c];
    out[gid] = acc * inv + b[c];
}

extern "C" void kernel_launch(void* const* d_in, const int* in_sizes, int n_in,
                              void* d_out, int out_size, void* d_ws, size_t ws_size,
                              hipStream_t stream) {
    const int*   x_idx  = (const int*)d_in[0];
    const int*   ei     = (const int*)d_in[1];
    const int*   et     = (const int*)d_in[2];
    const int*   batch  = (const int*)d_in[3];
    const float* semb   = (const float*)d_in[4];
    const float* cemb   = (const float*)d_in[5];
    const float* lin0w  = (const float*)d_in[6];
    const float* lin0b  = (const float*)d_in[7];
    const float* r1wrel = (const float*)d_in[8];
    const float* r1wroot= (const float*)d_in[9];
    const float* r1b    = (const float*)d_in[10];
    const float* r2wrel = (const float*)d_in[11];
    const float* r2wroot= (const float*)d_in[12];
    const float* r2b    = (const float*)d_in[13];
    const float* clsw   = (const float*)d_in[14];
    const float* clsb   = (const float*)d_in[15];
    float* out = (float*)d_out;

    char* ws = (char*)d_ws;
    size_t o = 0;
    auto alloc = [&](size_t bytes) -> void* {
        void* p = ws + o;
        o += (bytes + 255) & ~(size_t)255;
        return p;
    };
    int*   off  = (int*)  alloc((size_t)(NSEG + 1) * 4);
    int*   pos  = (int*)  alloc((size_t)NSEG * 4);
    int*   cnt  = (int*)  alloc((size_t)NSEG * 4);
    int*   bsum = (int*)  alloc((size_t)SCAN_NB * 4);
    int*   goff = (int*)  alloc((size_t)SCAN_NB * 4);
    int*   esrc = (int*)  alloc((size_t)NE * 4);
    float* xA   = (float*)alloc((size_t)NN * 64 * 4);
    float* xB   = (float*)alloc((size_t)NN * 64 * 4);
    float* Kbuf = (float*)alloc((size_t)NN * 256 * 4);
    float* psum = (float*)alloc((size_t)NG * 64 * 4);
    int*   pcnt = (int*)  alloc((size_t)NG * 4);

    hipMemsetAsync(cnt, 0, (size_t)NSEG * 4, stream);
    hipMemsetAsync(psum, 0, (size_t)NG * 64 * 4, stream);
    hipMemsetAsync(pcnt, 0, (size_t)NG * 4, stream);

    // node features
    k_embed<<<NN * 64 / 256, 256, 0, stream>>>(x_idx, semb, cemb, lin0w, lin0b, xA);

    // CSR (built once, reused for both layers)
    k_hist<<<NE / 256, 256, 0, stream>>>(ei, et, cnt);
    k_scan_reduce<<<SCAN_NB, 256, 0, stream>>>(cnt, bsum);
    k_scan_top<<<1, 512, 0, stream>>>(bsum, goff, off + NSEG);
    k_scan_final<<<SCAN_NB, 256, 0, stream>>>(cnt, goff, off, pos);
    k_scatter<<<NE / 256, 256, 0, stream>>>(ei, et, pos, esrc);

    // layer 1
    k_agg<<<NN / 4, 256, 0, stream>>>(xA, off, esrc, Kbuf);
    k_transform<<<(NN + 63) / 64, 512, 0, stream>>>(Kbuf, r1wrel, r1wroot, r1b, xB);
    // layer 2
    k_agg<<<NN / 4, 256, 0, stream>>>(xB, off, esrc, Kbuf);
    k_transform<<<(NN + 63) / 64, 512, 0, stream>>>(Kbuf, r2wrel, r2wroot, r2b, xA);

    // pool + classify
    {
        int nwaves = (NN + POOL_CHUNK - 1) / POOL_CHUNK;        // 3125
        int nblk = (nwaves * 64 + 255) / 256;                   // 782
        k_pool<<<nblk, 256, 0, stream>>>(xA, batch, psum, pcnt);
    }
    k_cls<<<(NG * 10 + 255) / 256, 256, 0, stream>>>(psum, pcnt, clsw, clsb, out);
}